// Round 1
// baseline (14475.887 us; speedup 1.0000x reference)
//
#include <hip/hip_runtime.h>
#include <math.h>

#define NB 256
#define TT 64
#define DD 1024
#define HH 1024
#define FOURH 4096

// ---------------- init: h0 = c0 = mean_k A[n,h,k] ----------------
__global__ __launch_bounds__(256) void init_hc(const float* __restrict__ A,
                                               float* __restrict__ h,
                                               float* __restrict__ c) {
    int idx = blockIdx.x * blockDim.x + threadIdx.x;   // n*H + hh
    if (idx >= NB * HH) return;
    const float* ap = A + (size_t)idx * 16;
    float s = 0.f;
#pragma unroll
    for (int k = 0; k < 16; ++k) s += ap[k];
    s *= (1.0f / 16.0f);
    h[idx] = s;
    c[idx] = s;
}

// ---------------- attention: scores -> softmax -> attn ----------------
// one block per sample n; 256 threads; each thread owns 4 h-rows.
__global__ __launch_bounds__(256) void attn_kernel(const float* __restrict__ A,
                                                   const float* __restrict__ h,
                                                   float* __restrict__ attn) {
    int n = blockIdx.x;
    int tid = threadIdx.x;
    int lane = tid & 63;
    int wave = tid >> 6;

    const float* An = A + (size_t)n * HH * 16;
    const float* hn = h + (size_t)n * HH;

    float areg[4][16];
    float part[16];
#pragma unroll
    for (int k = 0; k < 16; ++k) part[k] = 0.f;

#pragma unroll
    for (int i = 0; i < 4; ++i) {
        int hh = tid + i * 256;
        float hv = hn[hh];
        const float* ap = An + (size_t)hh * 16;
#pragma unroll
        for (int k = 0; k < 16; ++k) {
            float av = ap[k];
            areg[i][k] = av;
            part[k] += hv * av;
        }
    }

    __shared__ float red[4 * 16];
    // wave-level reduce each of the 16 partials
#pragma unroll
    for (int k = 0; k < 16; ++k) {
        float v = part[k];
#pragma unroll
        for (int off = 32; off > 0; off >>= 1) v += __shfl_down(v, off);
        if (lane == 0) red[wave * 16 + k] = v;
    }
    __syncthreads();

    // every thread redundantly computes softmax over the 16 scores
    float w[16];
    float mx = -1e30f;
#pragma unroll
    for (int k = 0; k < 16; ++k) {
        float s = (red[0 * 16 + k] + red[1 * 16 + k] + red[2 * 16 + k] + red[3 * 16 + k]) * 0.03125f;
        w[k] = s;
        mx = fmaxf(mx, s);
    }
    float sum = 0.f;
#pragma unroll
    for (int k = 0; k < 16; ++k) {
        w[k] = expf(w[k] - mx);
        sum += w[k];
    }
    float inv = 1.0f / sum;
#pragma unroll
    for (int k = 0; k < 16; ++k) w[k] *= inv;

    float* an = attn + (size_t)n * HH;
#pragma unroll
    for (int i = 0; i < 4; ++i) {
        float s = 0.f;
#pragma unroll
        for (int k = 0; k < 16; ++k) s += areg[i][k] * w[k];
        an[tid + i * 256] = s;
    }
}

// ---------------- per-step GEMM: a = [x_t, h, attn] @ [Wx; Wh; Wattn] ----------------
#define BM 32
#define BN 64
#define BK 16
// grid (FOURH/BN, NB/BM) = (64, 8); block 256 (16x16), each thread 2x4
__global__ __launch_bounds__(256) void gemm_step(const float* __restrict__ x,
                                                 const float* __restrict__ h,
                                                 const float* __restrict__ attn,
                                                 const float* __restrict__ Wx,
                                                 const float* __restrict__ Wh,
                                                 const float* __restrict__ Wattn,
                                                 float* __restrict__ a, int t) {
    __shared__ float As[BM][BK + 1];   // +1 pad: break 4-way bank alias on column reads
    __shared__ float Bs[BK][BN];

    int tid = threadIdx.x;
    int tx = tid & 15;
    int ty = tid >> 4;
    int row0 = blockIdx.y * BM;
    int col0 = blockIdx.x * BN;

    float acc[2][4] = {{0.f, 0.f, 0.f, 0.f}, {0.f, 0.f, 0.f, 0.f}};

    for (int k0 = 0; k0 < 3072; k0 += BK) {
        int seg = k0 >> 10;         // 0: x, 1: h, 2: attn
        int klocal = k0 & 1023;

        const float* aptr;
        size_t rstride;
        if (seg == 0) { aptr = x + (size_t)row0 * TT * DD + (size_t)t * DD + klocal; rstride = (size_t)TT * DD; }
        else if (seg == 1) { aptr = h + (size_t)row0 * HH + klocal; rstride = HH; }
        else { aptr = attn + (size_t)row0 * HH + klocal; rstride = HH; }

        // load A-tile: 32x16 = 512 elems, 2 per thread
#pragma unroll
        for (int e = 0; e < 2; ++e) {
            int idx = tid + e * 256;
            int r = idx >> 4, cc = idx & 15;
            As[r][cc] = aptr[(size_t)r * rstride + cc];
        }

        const float* wbase = (seg == 0) ? Wx : (seg == 1) ? Wh : Wattn;
        const float* wptr = wbase + (size_t)klocal * FOURH + col0;
        // load B-tile: 16x64 = 1024 elems, 4 per thread (fully coalesced along cols)
#pragma unroll
        for (int e = 0; e < 4; ++e) {
            int idx = tid + e * 256;
            int r = idx >> 6, cc = idx & 63;
            Bs[r][cc] = wptr[(size_t)r * FOURH + cc];
        }
        __syncthreads();

#pragma unroll
        for (int kk = 0; kk < BK; ++kk) {
            float4 bv = *reinterpret_cast<const float4*>(&Bs[kk][tx * 4]);
#pragma unroll
            for (int i = 0; i < 2; ++i) {
                float av = As[ty * 2 + i][kk];
                acc[i][0] += av * bv.x;
                acc[i][1] += av * bv.y;
                acc[i][2] += av * bv.z;
                acc[i][3] += av * bv.w;
            }
        }
        __syncthreads();
    }

#pragma unroll
    for (int i = 0; i < 2; ++i) {
        float* arow = a + (size_t)(row0 + ty * 2 + i) * FOURH + col0 + tx * 4;
        arow[0] = acc[i][0];
        arow[1] = acc[i][1];
        arow[2] = acc[i][2];
        arow[3] = acc[i][3];
    }
}

// ---------------- gates + LSTM state update + output write ----------------
__global__ __launch_bounds__(256) void gates_kernel(const float* __restrict__ a,
                                                    const float* __restrict__ b,
                                                    float* __restrict__ h,
                                                    float* __restrict__ c,
                                                    float* __restrict__ out, int t) {
    int idx = blockIdx.x * blockDim.x + threadIdx.x;   // n*H + hh
    if (idx >= NB * HH) return;
    int n = idx >> 10;
    int hh = idx & 1023;
    const float* arow = a + (size_t)n * FOURH;

    float ai = arow[hh]          + b[hh];
    float af = arow[hh + 1024]   + b[hh + 1024];
    float ao = arow[hh + 2048]   + b[hh + 2048];
    float ag = arow[hh + 3072]   + b[hh + 3072];

    float ig = 1.f / (1.f + expf(-ai));
    float fg = 1.f / (1.f + expf(-af));
    float og = 1.f / (1.f + expf(-ao));
    float gg = tanhf(ag);

    float cn = fg * c[idx] + ig * gg;
    float hn = og * tanhf(cn);
    c[idx] = cn;
    h[idx] = hn;
    out[((size_t)n * TT + t) * HH + hh] = hn;
}

extern "C" void kernel_launch(void* const* d_in, const int* in_sizes, int n_in,
                              void* d_out, int out_size, void* d_ws, size_t ws_size,
                              hipStream_t stream) {
    const float* x     = (const float*)d_in[0];
    const float* A     = (const float*)d_in[1];
    const float* Wx    = (const float*)d_in[2];
    const float* Wh    = (const float*)d_in[3];
    const float* Wattn = (const float*)d_in[4];
    const float* b     = (const float*)d_in[5];
    float* out = (float*)d_out;

    float* ws   = (float*)d_ws;
    float* h    = ws;                        // NB*HH
    float* c    = h + (size_t)NB * HH;       // NB*HH
    float* attn = c + (size_t)NB * HH;       // NB*HH
    float* a    = attn + (size_t)NB * HH;    // NB*FOURH

    init_hc<<<(NB * HH + 255) / 256, 256, 0, stream>>>(A, h, c);

    dim3 ggrid(FOURH / BN, NB / BM);
    for (int t = 0; t < TT; ++t) {
        attn_kernel<<<NB, 256, 0, stream>>>(A, h, attn);
        gemm_step<<<ggrid, 256, 0, stream>>>(x, h, attn, Wx, Wh, Wattn, a, t);
        gates_kernel<<<(NB * HH + 255) / 256, 256, 0, stream>>>(a, b, h, c, out, t);
    }
}

// Round 2
// 3926.003 us; speedup vs baseline: 3.6872x; 3.6872x over previous
//
#include <hip/hip_runtime.h>
#include <math.h>

#define NB 256
#define TT 64
#define DD 1024
#define HH 1024
#define FOURH 4096
#define KTOT 3072

#define WTL 12582912ull          // per-level elems of WT: 4096*3072
#define ABFL 786432ull           // per-level elems of Abf: 256*3072
#define P1 (NB * FOURH)          // one partial plane

typedef short bf16x8 __attribute__((ext_vector_type(8)));
typedef float f32x4 __attribute__((ext_vector_type(4)));

__device__ __forceinline__ unsigned short f2b(float f) {
    unsigned int u = __float_as_uint(f);
    unsigned int r = (u + 0x7FFFu + ((u >> 16) & 1u)) >> 16;
    return (unsigned short)r;
}
__device__ __forceinline__ float b2f(unsigned short s) {
    return __uint_as_float(((unsigned int)s) << 16);
}
__device__ __forceinline__ void split3(float f, unsigned short& hi, unsigned short& mi, unsigned short& lo) {
    hi = f2b(f);
    float r1 = f - b2f(hi);
    mi = f2b(r1);
    float r2 = r1 - b2f(mi);
    lo = f2b(r2);
}

// ---------------- weight split+transpose: W[k][j] f32 -> WT[lvl][j][k] bf16 ----------------
__global__ __launch_bounds__(256) void wsplit_kernel(const float* __restrict__ Wx,
                                                     const float* __restrict__ Wh,
                                                     const float* __restrict__ Wattn,
                                                     unsigned short* __restrict__ WT) {
    __shared__ float tile[32][33];
    int k0 = blockIdx.x * 32, j0 = blockIdx.y * 32;
    int t = threadIdx.x;
    int rl = t >> 3, c4 = (t & 7) * 4;
    int seg = k0 >> 10;
    const float* W = (seg == 0) ? Wx : (seg == 1) ? Wh : Wattn;
    const float4 v = *reinterpret_cast<const float4*>(W + (size_t)((k0 & 1023) + rl) * FOURH + j0 + c4);
    tile[rl][c4 + 0] = v.x; tile[rl][c4 + 1] = v.y; tile[rl][c4 + 2] = v.z; tile[rl][c4 + 3] = v.w;
    __syncthreads();
    int jl = t >> 3, k4 = (t & 7) * 4;
    unsigned short s[4][3];
#pragma unroll
    for (int i = 0; i < 4; ++i) split3(tile[k4 + i][jl], s[i][0], s[i][1], s[i][2]);
    size_t off = (size_t)(j0 + jl) * KTOT + k0 + k4;
#pragma unroll
    for (int lvl = 0; lvl < 3; ++lvl) {
        uint2 p;
        p.x = (unsigned)s[0][lvl] | ((unsigned)s[1][lvl] << 16);
        p.y = (unsigned)s[2][lvl] | ((unsigned)s[3][lvl] << 16);
        *reinterpret_cast<uint2*>(WT + (size_t)lvl * WTL + off) = p;
    }
}

// ---------------- init: h0 = c0 = mean_k A[n,h,k]; also write h splits ----------------
__global__ __launch_bounds__(256) void init_hc(const float* __restrict__ A,
                                               float* __restrict__ h,
                                               float* __restrict__ c,
                                               unsigned short* __restrict__ Abf) {
    int idx = blockIdx.x * blockDim.x + threadIdx.x;
    if (idx >= NB * HH) return;
    const float* ap = A + (size_t)idx * 16;
    float s = 0.f;
#pragma unroll
    for (int k = 0; k < 16; ++k) s += ap[k];
    s *= (1.0f / 16.0f);
    h[idx] = s;
    c[idx] = s;
    int n = idx >> 10, hh = idx & 1023;
    unsigned short hb, mb, lb;
    split3(s, hb, mb, lb);
    size_t o = (size_t)n * KTOT + 1024 + hh;
    Abf[o] = hb;
    Abf[ABFL + o] = mb;
    Abf[2 * ABFL + o] = lb;
}

// ---------------- attention: scores -> softmax -> attn (written as bf16x3 splits) ----------------
__global__ __launch_bounds__(256) void attn_kernel(const float* __restrict__ A,
                                                   const float* __restrict__ h,
                                                   unsigned short* __restrict__ Abf) {
    int n = blockIdx.x;
    int tid = threadIdx.x;
    int lane = tid & 63;
    int wave = tid >> 6;

    const float* An = A + (size_t)n * HH * 16;
    const float* hn = h + (size_t)n * HH;

    float areg[4][16];
    float part[16];
#pragma unroll
    for (int k = 0; k < 16; ++k) part[k] = 0.f;

#pragma unroll
    for (int i = 0; i < 4; ++i) {
        int hh = tid + i * 256;
        float hv = hn[hh];
        const float* ap = An + (size_t)hh * 16;
#pragma unroll
        for (int k = 0; k < 16; ++k) {
            float av = ap[k];
            areg[i][k] = av;
            part[k] += hv * av;
        }
    }

    __shared__ float red[4 * 16];
#pragma unroll
    for (int k = 0; k < 16; ++k) {
        float v = part[k];
#pragma unroll
        for (int off = 32; off > 0; off >>= 1) v += __shfl_down(v, off);
        if (lane == 0) red[wave * 16 + k] = v;
    }
    __syncthreads();

    float w[16];
    float mx = -1e30f;
#pragma unroll
    for (int k = 0; k < 16; ++k) {
        float s = (red[0 * 16 + k] + red[1 * 16 + k] + red[2 * 16 + k] + red[3 * 16 + k]) * 0.03125f;
        w[k] = s;
        mx = fmaxf(mx, s);
    }
    float sum = 0.f;
#pragma unroll
    for (int k = 0; k < 16; ++k) {
        w[k] = expf(w[k] - mx);
        sum += w[k];
    }
    float inv = 1.0f / sum;
#pragma unroll
    for (int k = 0; k < 16; ++k) w[k] *= inv;

#pragma unroll
    for (int i = 0; i < 4; ++i) {
        float s = 0.f;
#pragma unroll
        for (int k = 0; k < 16; ++k) s += areg[i][k] * w[k];
        int hh = tid + i * 256;
        unsigned short hb, mb, lb;
        split3(s, hb, mb, lb);
        size_t o = (size_t)n * KTOT + 2048 + hh;
        Abf[o] = hb;
        Abf[ABFL + o] = mb;
        Abf[2 * ABFL + o] = lb;
    }
}

// ---------------- per-step x_t split into Abf[.., 0..1024) ----------------
__global__ __launch_bounds__(256) void prep_x(const float* __restrict__ x,
                                              unsigned short* __restrict__ Abf, int t) {
    int idx = blockIdx.x * 256 + threadIdx.x;   // 65536 threads, 4 elems each
    int n = idx >> 8;
    int c4 = (idx & 255) * 4;
    const float4 v = *reinterpret_cast<const float4*>(x + ((size_t)n * TT + t) * DD + c4);
    float f[4] = {v.x, v.y, v.z, v.w};
    unsigned short s[4][3];
#pragma unroll
    for (int i = 0; i < 4; ++i) split3(f[i], s[i][0], s[i][1], s[i][2]);
    size_t o = (size_t)n * KTOT + c4;
#pragma unroll
    for (int lvl = 0; lvl < 3; ++lvl) {
        uint2 p;
        p.x = (unsigned)s[0][lvl] | ((unsigned)s[1][lvl] << 16);
        p.y = (unsigned)s[2][lvl] | ((unsigned)s[3][lvl] << 16);
        *reinterpret_cast<uint2*>(Abf + (size_t)lvl * ABFL + o) = p;
    }
}

// ---------------- MFMA step GEMM: apart[z] = Abf_z-slice @ WT ----------------
#define GBM 64
#define GBN 64
#define GBK 64
#define KSPLIT 2
#define KHALF (KTOT / KSPLIT)

__global__ __launch_bounds__(512, 4) void gemm_mfma(const unsigned short* __restrict__ Abf,
                                                    const unsigned short* __restrict__ WT,
                                                    float* __restrict__ apart) {
    __shared__ __align__(16) short Asm[3][GBM * GBK];
    __shared__ __align__(16) short Bsm[3][GBN * GBK];
    int tid = threadIdx.x;
    int col0 = blockIdx.x * GBN;
    int row0 = blockIdx.y * GBM;
    int kbeg = blockIdx.z * KHALF;
    int l = tid & 63;
    int w = tid >> 6;
    int wm = w >> 2, wn = w & 3;        // wave tile: 32 rows x 16 cols
    int lr = l & 15, lk = l >> 4;

    f32x4 acc[2] = {{0.f, 0.f, 0.f, 0.f}, {0.f, 0.f, 0.f, 0.f}};

    int sr = tid >> 3, sc = tid & 7;    // staging: row 0..63, 16B-slot 0..7
    int ssl = (sc ^ (sr & 7)) * 8;

    for (int k0 = kbeg; k0 < kbeg + KHALF; k0 += GBK) {
#pragma unroll
        for (int lvl = 0; lvl < 3; ++lvl) {
            uint4 av = *reinterpret_cast<const uint4*>(Abf + (size_t)lvl * ABFL + (size_t)(row0 + sr) * KTOT + k0 + sc * 8);
            *reinterpret_cast<uint4*>(&Asm[lvl][sr * GBK + ssl]) = av;
            uint4 bv = *reinterpret_cast<const uint4*>(WT + (size_t)lvl * WTL + (size_t)(col0 + sr) * KTOT + k0 + sc * 8);
            *reinterpret_cast<uint4*>(&Bsm[lvl][sr * GBK + ssl]) = bv;
        }
        __syncthreads();
#pragma unroll
        for (int kk = 0; kk < 2; ++kk) {
            int brow = wn * 16 + lr;
            int bsl = ((kk * 4 + lk) ^ (brow & 7)) * 8;
            bf16x8 bfr[3];
#pragma unroll
            for (int lvl = 0; lvl < 3; ++lvl)
                bfr[lvl] = *reinterpret_cast<const bf16x8*>(&Bsm[lvl][brow * GBK + bsl]);
#pragma unroll
            for (int mm = 0; mm < 2; ++mm) {
                int arow = wm * 32 + mm * 16 + lr;
                int asl = ((kk * 4 + lk) ^ (arow & 7)) * 8;
                bf16x8 afr[3];
#pragma unroll
                for (int lvl = 0; lvl < 3; ++lvl)
                    afr[lvl] = *reinterpret_cast<const bf16x8*>(&Asm[lvl][arow * GBK + asl]);
                // 6-product bf16x3: hi*hi, hi*mid, mid*hi, hi*lo, lo*hi, mid*mid
                acc[mm] = __builtin_amdgcn_mfma_f32_16x16x32_bf16(afr[0], bfr[0], acc[mm], 0, 0, 0);
                acc[mm] = __builtin_amdgcn_mfma_f32_16x16x32_bf16(afr[0], bfr[1], acc[mm], 0, 0, 0);
                acc[mm] = __builtin_amdgcn_mfma_f32_16x16x32_bf16(afr[1], bfr[0], acc[mm], 0, 0, 0);
                acc[mm] = __builtin_amdgcn_mfma_f32_16x16x32_bf16(afr[0], bfr[2], acc[mm], 0, 0, 0);
                acc[mm] = __builtin_amdgcn_mfma_f32_16x16x32_bf16(afr[2], bfr[0], acc[mm], 0, 0, 0);
                acc[mm] = __builtin_amdgcn_mfma_f32_16x16x32_bf16(afr[1], bfr[1], acc[mm], 0, 0, 0);
            }
        }
        __syncthreads();
    }

    float* ap = apart + (size_t)blockIdx.z * (size_t)P1;
    int cg = col0 + wn * 16 + lr;
#pragma unroll
    for (int mm = 0; mm < 2; ++mm) {
        int rb = row0 + wm * 32 + mm * 16 + lk * 4;
#pragma unroll
        for (int i = 0; i < 4; ++i)
            ap[(size_t)(rb + i) * FOURH + cg] = acc[mm][i];
    }
}

// ---------------- gates + LSTM update + output + h splits ----------------
__global__ __launch_bounds__(256) void gates_kernel(const float* __restrict__ apart,
                                                    const float* __restrict__ b,
                                                    float* __restrict__ h,
                                                    float* __restrict__ c,
                                                    unsigned short* __restrict__ Abf,
                                                    float* __restrict__ out, int t) {
    int idx = blockIdx.x * blockDim.x + threadIdx.x;
    if (idx >= NB * HH) return;
    int n = idx >> 10;
    int hh = idx & 1023;
    const float* a0 = apart + (size_t)n * FOURH;
    const float* a1 = a0 + (size_t)P1;

    float ai = a0[hh] + a1[hh] + b[hh];
    float af = a0[hh + 1024] + a1[hh + 1024] + b[hh + 1024];
    float ao = a0[hh + 2048] + a1[hh + 2048] + b[hh + 2048];
    float ag = a0[hh + 3072] + a1[hh + 3072] + b[hh + 3072];

    float ig = 1.f / (1.f + expf(-ai));
    float fg = 1.f / (1.f + expf(-af));
    float og = 1.f / (1.f + expf(-ao));
    float gg = tanhf(ag);

    float cn = fg * c[idx] + ig * gg;
    float hn = og * tanhf(cn);
    c[idx] = cn;
    h[idx] = hn;
    out[((size_t)n * TT + t) * HH + hh] = hn;

    unsigned short hb, mb, lb;
    split3(hn, hb, mb, lb);
    size_t o = (size_t)n * KTOT + 1024 + hh;
    Abf[o] = hb;
    Abf[ABFL + o] = mb;
    Abf[2 * ABFL + o] = lb;
}

extern "C" void kernel_launch(void* const* d_in, const int* in_sizes, int n_in,
                              void* d_out, int out_size, void* d_ws, size_t ws_size,
                              hipStream_t stream) {
    const float* x     = (const float*)d_in[0];
    const float* A     = (const float*)d_in[1];
    const float* Wx    = (const float*)d_in[2];
    const float* Wh    = (const float*)d_in[3];
    const float* Wattn = (const float*)d_in[4];
    const float* b     = (const float*)d_in[5];
    float* out = (float*)d_out;

    unsigned short* WT  = (unsigned short*)d_ws;          // 3 * 4096*3072 bf16 = 72 MB
    unsigned short* Abf = WT + 3 * WTL;                   // 3 * 256*3072 bf16 = 4.5 MB
    float* apart = (float*)(Abf + 3 * ABFL);              // 2 * 256*4096 f32 = 8 MB
    float* h = apart + 2 * (size_t)P1;                    // 1 MB
    float* c = h + (size_t)NB * HH;                       // 1 MB

    wsplit_kernel<<<dim3(KTOT / 32, FOURH / 32), 256, 0, stream>>>(Wx, Wh, Wattn, WT);
    init_hc<<<(NB * HH + 255) / 256, 256, 0, stream>>>(A, h, c, Abf);

    dim3 ggrid(FOURH / GBN, NB / GBM, KSPLIT);
    for (int t = 0; t < TT; ++t) {
        attn_kernel<<<NB, 256, 0, stream>>>(A, h, Abf);
        prep_x<<<NB, 256, 0, stream>>>(x, Abf, t);
        gemm_mfma<<<ggrid, 512, 0, stream>>>(Abf, WT, apart);
        gates_kernel<<<(NB * HH + 255) / 256, 256, 0, stream>>>(apart, b, h, c, Abf, out, t);
    }
}

// Round 3
// 3417.301 us; speedup vs baseline: 4.2361x; 1.1489x over previous
//
#include <hip/hip_runtime.h>
#include <math.h>

#define NB 256
#define TT 64
#define DD 1024
#define HH 1024
#define FOURH 4096
#define KTOT 3072
#define KT96 96                   // K-tiles of 32
#define P1 (NB * FOURH)           // one partial plane (f32 elems)

#define AF_LVL 786432ull          // 16 rt * 96 kt * 512 = elems per level of A-frags
#define BF_LVL 12582912ull        // 256 ct * 96 kt * 512 = elems per level of B-frags

typedef short bf16x8 __attribute__((ext_vector_type(8)));
typedef float f32x4 __attribute__((ext_vector_type(4)));

__device__ __forceinline__ unsigned short f2b(float f) {
    unsigned int u = __float_as_uint(f);
    unsigned int r = (u + 0x7FFFu + ((u >> 16) & 1u)) >> 16;
    return (unsigned short)r;
}
__device__ __forceinline__ float b2f(unsigned short s) {
    return __uint_as_float(((unsigned int)s) << 16);
}
__device__ __forceinline__ void split3(float f, unsigned short& hi, unsigned short& mi, unsigned short& lo) {
    hi = f2b(f);
    float r1 = f - b2f(hi);
    mi = f2b(r1);
    float r2 = r1 - b2f(mi);
    lo = f2b(r2);
}

// fragment offsets (elems). A-frag: lane l holds A[row=l&15][k0+8*(l>>4)+0..7]
__device__ __forceinline__ size_t aoff(int lvl, int rt, int kt, int lane) {
    return ((size_t)((lvl * 16 + rt) * KT96 + kt) * 64 + lane) * 8;
}
__device__ __forceinline__ size_t boff(int lvl, int ct, int kt, int lane) {
    return ((size_t)((lvl * 256 + ct) * KT96 + kt) * 64 + lane) * 8;
}

// split 8 consecutive k-values (k8 8-aligned) of row n into the 3 A-frag levels
__device__ __forceinline__ void write_frag8(unsigned short* __restrict__ Af, int n, int k8, const float* v) {
    int rt = n >> 4, kt = k8 >> 5;
    int lane = (n & 15) + 16 * ((k8 >> 3) & 3);
    unsigned short s[8][3];
#pragma unroll
    for (int i = 0; i < 8; ++i) split3(v[i], s[i][0], s[i][1], s[i][2]);
#pragma unroll
    for (int lvl = 0; lvl < 3; ++lvl) {
        uint4 p;
        p.x = (unsigned)s[0][lvl] | ((unsigned)s[1][lvl] << 16);
        p.y = (unsigned)s[2][lvl] | ((unsigned)s[3][lvl] << 16);
        p.z = (unsigned)s[4][lvl] | ((unsigned)s[5][lvl] << 16);
        p.w = (unsigned)s[6][lvl] | ((unsigned)s[7][lvl] << 16);
        *reinterpret_cast<uint4*>(Af + aoff(lvl, rt, kt, lane)) = p;
    }
}

// ---------------- weight split: W[k][j] f32 -> B-fragment order ----------------
__global__ __launch_bounds__(256) void wsplit_kernel(const float* __restrict__ Wx,
                                                     const float* __restrict__ Wh,
                                                     const float* __restrict__ Wattn,
                                                     unsigned short* __restrict__ Bf) {
    __shared__ float tile[32][33];
    int k0 = blockIdx.x * 32, j0 = blockIdx.y * 32;
    int t = threadIdx.x;
    int rl = t >> 3, c4 = (t & 7) * 4;
    int seg = k0 >> 10;
    const float* W = (seg == 0) ? Wx : (seg == 1) ? Wh : Wattn;
    const float4 v = *reinterpret_cast<const float4*>(W + (size_t)((k0 & 1023) + rl) * FOURH + j0 + c4);
    tile[rl][c4 + 0] = v.x; tile[rl][c4 + 1] = v.y; tile[rl][c4 + 2] = v.z; tile[rl][c4 + 3] = v.w;
    __syncthreads();
    int jl = t >> 3, k4 = (t & 7) * 4;
    unsigned short s[4][3];
#pragma unroll
    for (int i = 0; i < 4; ++i) split3(tile[k4 + i][jl], s[i][0], s[i][1], s[i][2]);
    int j = j0 + jl;
    int kg = k0 + k4;
    int ct = j >> 4, kt = kg >> 5;
    int lane = (j & 15) + 16 * ((kg >> 3) & 3);
    int sub = kg & 7;   // 0 or 4
#pragma unroll
    for (int lvl = 0; lvl < 3; ++lvl) {
        uint2 p;
        p.x = (unsigned)s[0][lvl] | ((unsigned)s[1][lvl] << 16);
        p.y = (unsigned)s[2][lvl] | ((unsigned)s[3][lvl] << 16);
        *reinterpret_cast<uint2*>(Bf + boff(lvl, ct, kt, lane) + sub) = p;
    }
}

// ---------------- shared device phases ----------------
// attention: scores over 16 keys from hsh -> softmax -> ash
__device__ __forceinline__ void attn_phase(const float* __restrict__ A, int n, int tid,
                                           const float* hsh, float* ash, float* red2) {
    int lane = tid & 63, wave = tid >> 6;
    const float* An = A + (size_t)n * HH * 16;
    float areg[4][16];
    float part[16];
#pragma unroll
    for (int k = 0; k < 16; ++k) part[k] = 0.f;
#pragma unroll
    for (int i = 0; i < 4; ++i) {
        int hh = tid + i * 256;
        float hv = hsh[hh];
        const float* ap = An + (size_t)hh * 16;
#pragma unroll
        for (int k = 0; k < 16; ++k) {
            float av = ap[k];
            areg[i][k] = av;
            part[k] += hv * av;
        }
    }
#pragma unroll
    for (int k = 0; k < 16; ++k) {
        float v = part[k];
#pragma unroll
        for (int off = 32; off > 0; off >>= 1) v += __shfl_down(v, off);
        if (lane == 0) red2[wave * 16 + k] = v;
    }
    __syncthreads();
    float w[16];
    float mx = -1e30f;
#pragma unroll
    for (int k = 0; k < 16; ++k) {
        float s = (red2[k] + red2[16 + k] + red2[32 + k] + red2[48 + k]) * 0.03125f;
        w[k] = s;
        mx = fmaxf(mx, s);
    }
    float sum = 0.f;
#pragma unroll
    for (int k = 0; k < 16; ++k) {
        w[k] = expf(w[k] - mx);
        sum += w[k];
    }
    float inv = 1.0f / sum;
#pragma unroll
    for (int k = 0; k < 16; ++k) w[k] *= inv;
#pragma unroll
    for (int i = 0; i < 4; ++i) {
        float s = 0.f;
#pragma unroll
        for (int k = 0; k < 16; ++k) s += areg[i][k] * w[k];
        ash[tid + i * 256] = s;
    }
}

// write h (k=1024+), attn (k=2048+), x_{tnext} (k=0+) fragments
__device__ __forceinline__ void write_state_frags(unsigned short* __restrict__ Af,
                                                  const float* __restrict__ x,
                                                  const float* hsh, const float* ash,
                                                  int n, int tnext, int tid) {
    if (tid >= 128) return;
    int k8 = tid * 8;
    float v[8];
#pragma unroll
    for (int i = 0; i < 8; ++i) v[i] = hsh[k8 + i];
    write_frag8(Af, n, 1024 + k8, v);
#pragma unroll
    for (int i = 0; i < 8; ++i) v[i] = ash[k8 + i];
    write_frag8(Af, n, 2048 + k8, v);
    if (tnext < TT) {
        const float4* xp = reinterpret_cast<const float4*>(x + ((size_t)n * TT + tnext) * DD + k8);
        float4 x0 = xp[0], x1 = xp[1];
        v[0] = x0.x; v[1] = x0.y; v[2] = x0.z; v[3] = x0.w;
        v[4] = x1.x; v[5] = x1.y; v[6] = x1.z; v[7] = x1.w;
        write_frag8(Af, n, k8, v);
    }
}

// ---------------- init: h0 = c0 = mean_k A; attn0; x0 frags ----------------
__global__ __launch_bounds__(256) void initk(const float* __restrict__ A,
                                             const float* __restrict__ x,
                                             float* __restrict__ c,
                                             unsigned short* __restrict__ Af) {
    int n = blockIdx.x, tid = threadIdx.x;
    __shared__ float hsh[HH], ash[HH];
    __shared__ float red2[64];
#pragma unroll
    for (int i = 0; i < 4; ++i) {
        int hh = tid + i * 256;
        const float* ap = A + ((size_t)n * HH + hh) * 16;
        float s = 0.f;
#pragma unroll
        for (int k = 0; k < 16; ++k) s += ap[k];
        s *= (1.0f / 16.0f);
        c[(size_t)n * HH + hh] = s;
        hsh[hh] = s;
    }
    __syncthreads();
    attn_phase(A, n, tid, hsh, ash, red2);
    __syncthreads();
    write_state_frags(Af, x, hsh, ash, n, 0, tid);
}

// ---------------- MFMA GEMM: fragment-direct, no LDS staging ----------------
// grid 256 = (z 4) x (col 32) x (row 2); 512 thr = 8 waves (wm2 x wn2 x wk2)
__global__ __launch_bounds__(512, 2) void gemm_mfma(const unsigned short* __restrict__ Af,
                                                    const unsigned short* __restrict__ Bf,
                                                    float* __restrict__ apart) {
    int tid = threadIdx.x;
    int l = tid & 63, w = tid >> 6;
    int wm = w & 1, wn = (w >> 1) & 1, wk = w >> 2;
    int wg = blockIdx.x;
    int id = (wg & 7) * 32 + (wg >> 3);          // XCD-chunked swizzle (256 % 8 == 0)
    int rowb = id & 1, colb = (id >> 1) & 31, z = id >> 6;
    int rtb = rowb * 8 + wm * 4;
    int ctb = colb * 8 + wn * 4;
    int kt0 = z * 24 + wk * 12;

    f32x4 acc[4][4] = {};
    for (int kt = kt0; kt < kt0 + 12; ++kt) {
        bf16x8 afr[3][4], bfr[3][4];
#pragma unroll
        for (int lvl = 0; lvl < 3; ++lvl)
#pragma unroll
            for (int i = 0; i < 4; ++i) {
                afr[lvl][i] = *reinterpret_cast<const bf16x8*>(Af + aoff(lvl, rtb + i, kt, l));
                bfr[lvl][i] = *reinterpret_cast<const bf16x8*>(Bf + boff(lvl, ctb + i, kt, l));
            }
        const int pa[6] = {0, 0, 1, 0, 2, 1};
        const int pb[6] = {0, 1, 0, 2, 0, 1};
#pragma unroll
        for (int p = 0; p < 6; ++p)
#pragma unroll
            for (int mi = 0; mi < 4; ++mi)
#pragma unroll
                for (int ni = 0; ni < 4; ++ni)
                    acc[mi][ni] = __builtin_amdgcn_mfma_f32_16x16x32_bf16(afr[pa[p]][mi], bfr[pb[p]][ni], acc[mi][ni], 0, 0, 0);
    }

    __shared__ float red[4][16][256];            // 64 KB: wk=1 partials
    int q = wm * 2 + wn;
    if (wk == 1) {
#pragma unroll
        for (int mi = 0; mi < 4; ++mi)
#pragma unroll
            for (int ni = 0; ni < 4; ++ni)
                *reinterpret_cast<f32x4*>(&red[q][mi * 4 + ni][l * 4]) = acc[mi][ni];
    }
    __syncthreads();
    if (wk == 0) {
        float* plane = apart + (size_t)z * P1;
#pragma unroll
        for (int mi = 0; mi < 4; ++mi) {
            int rbase = rowb * 128 + wm * 64 + mi * 16 + (l >> 4) * 4;
#pragma unroll
            for (int ni = 0; ni < 4; ++ni) {
                f32x4 o = *reinterpret_cast<f32x4*>(&red[q][mi * 4 + ni][l * 4]);
                int cg = colb * 128 + wn * 64 + ni * 16 + (l & 15);
#pragma unroll
                for (int r = 0; r < 4; ++r)
                    plane[(size_t)(rbase + r) * FOURH + cg] = acc[mi][ni][r] + o[r];
            }
        }
    }
}

// ---------------- pointwise: gates + LSTM update + attn + frag writes ----------------
__global__ __launch_bounds__(256) void pointwise(const float* __restrict__ apart,
                                                 const float* __restrict__ bias,
                                                 const float* __restrict__ A,
                                                 const float* __restrict__ x,
                                                 float* __restrict__ c,
                                                 float* __restrict__ out,
                                                 unsigned short* __restrict__ Af, int t) {
    int n = blockIdx.x, tid = threadIdx.x;
    __shared__ float hsh[HH], ash[HH];
    __shared__ float red2[64];
    const float* ap = apart + (size_t)n * FOURH;
#pragma unroll
    for (int i = 0; i < 4; ++i) {
        int hh = i * 256 + tid;
        float g4[4];
#pragma unroll
        for (int g = 0; g < 4; ++g) {
            int j = g * 1024 + hh;
            float s = bias[j];
#pragma unroll
            for (int zz = 0; zz < 4; ++zz) s += ap[(size_t)zz * P1 + j];
            g4[g] = s;
        }
        float ig = 1.f / (1.f + expf(-g4[0]));
        float fg = 1.f / (1.f + expf(-g4[1]));
        float og = 1.f / (1.f + expf(-g4[2]));
        float gg = tanhf(g4[3]);
        float cn = fg * c[(size_t)n * HH + hh] + ig * gg;
        float hn = og * tanhf(cn);
        c[(size_t)n * HH + hh] = cn;
        out[((size_t)n * TT + t) * HH + hh] = hn;
        hsh[hh] = hn;
    }
    __syncthreads();
    attn_phase(A, n, tid, hsh, ash, red2);
    __syncthreads();
    write_state_frags(Af, x, hsh, ash, n, t + 1, tid);
}

extern "C" void kernel_launch(void* const* d_in, const int* in_sizes, int n_in,
                              void* d_out, int out_size, void* d_ws, size_t ws_size,
                              hipStream_t stream) {
    const float* x     = (const float*)d_in[0];
    const float* A     = (const float*)d_in[1];
    const float* Wx    = (const float*)d_in[2];
    const float* Wh    = (const float*)d_in[3];
    const float* Wattn = (const float*)d_in[4];
    const float* b     = (const float*)d_in[5];
    float* out = (float*)d_out;

    unsigned short* Bf = (unsigned short*)d_ws;        // 3*BF_LVL bf16 = 75.5 MB
    unsigned short* Af = Bf + 3 * BF_LVL;              // 3*AF_LVL bf16 = 4.7 MB
    float* apart = (float*)(Af + 3 * AF_LVL);          // 4 * NB*FOURH f32 = 16 MB
    float* c = apart + 4 * (size_t)P1;                 // 1 MB

    wsplit_kernel<<<dim3(KTOT / 32, FOURH / 32), 256, 0, stream>>>(Wx, Wh, Wattn, Bf);
    initk<<<NB, 256, 0, stream>>>(A, x, c, Af);

    for (int t = 0; t < TT; ++t) {
        gemm_mfma<<<256, 512, 0, stream>>>(Af, Bf, apart);
        pointwise<<<NB, 256, 0, stream>>>(apart, b, A, x, c, out, Af, t);
    }
}